// Round 21
// baseline (319.269 us; speedup 1.0000x reference)
//
#include <hip/hip_runtime.h>
#include <hip/hip_bf16.h>
#include <hip/hip_cooperative_groups.h>

namespace cg = cooperative_groups;

#define GD     50          // grid cells per dim
#define NC     (GD*GD*GD)  // 125000
#define CHUNK  250         // cells per offsets chunk; 250%50==0 keeps x-rows intact
#define CAPK   256         // in-radius candidate capacity per centroid
#define PREPB  1024        // cooperative prep grid (co-resident: 4 blocks/CU)
#define RADIUS_F 0.2f
#define R2SAFE 0.0401f

typedef unsigned long long ull;
typedef __attribute__((ext_vector_type(4))) _Float16 f16x4;
typedef __attribute__((ext_vector_type(8))) _Float16 f16x8;
typedef __attribute__((ext_vector_type(4))) float    f32x4;

__device__ __forceinline__ int cellcoord(float v) {
    int c = (int)floorf((v + 5.0f) * 5.0f);
    return min(max(c, 0), GD - 1);
}

// Fragment-order weight layout in wf16 (13312 f16):
//   [0,1024)      F1 [nn=4][lane=64][4]
//   [1024,3072)   FA2[nn=4][lane=64][8]
//   [3072,5120)   FB2[nn=4][lane=64][8]
//   [5120,9216)   FA3[nn=8][lane=64][8]
//   [9216,13312)  FB3[nn=8][lane=64][8]

// -------- K1: cooperative prep: zero -> count+weights -> offsets -> scatter
__global__ __launch_bounds__(256) void sa_prep_all(
    const float* __restrict__ vtx, const int* __restrict__ cidx,
    const float* __restrict__ W1, const float* __restrict__ W2,
    const float* __restrict__ W3,
    int* __restrict__ cellCnt, int* __restrict__ cellStart,
    int* __restrict__ cellEnd, int* __restrict__ cellCur,
    int* __restrict__ cursor,
    float4* __restrict__ sorted4, float4* __restrict__ cpos4,
    _Float16* __restrict__ wf16, int N, int M) {

    cg::grid_group grid = cg::this_grid();
    __shared__ int sc[256];
    __shared__ int base_s;

    int t = threadIdx.x;
    int tid = blockIdx.x * 256 + t;
    int stride = gridDim.x * 256;

    // ---- phase 0: zero cellCnt + cursor (contiguous) ----
    {
        int4* z4 = (int4*)cellCnt;
        int n4 = (NC * 4 + 16) / 16;
        for (int i = tid; i < n4; i += stride) z4[i] = make_int4(0, 0, 0, 0);
    }
    grid.sync();

    // ---- phase 1: count cells + pack frag-order f16 weights ----
    for (int p = tid; p < N; p += stride) {
        float x = vtx[3 * p], y = vtx[3 * p + 1], z = vtx[3 * p + 2];
        int cc = (cellcoord(z) * GD + cellcoord(y)) * GD + cellcoord(x);
        atomicAdd(&cellCnt[cc], 1);
    }
    for (int e = tid; e < 1024; e += stride) {
        int nn = e >> 8, lane = (e >> 2) & 63, j = e & 3;
        int col = nn * 16 + (lane & 15), k = (lane >> 4) * 4 + j;
        wf16[e] = (k < 6) ? (_Float16)W1[k * 64 + col] : (_Float16)0.f;
    }
    for (int e = tid; e < 2048; e += stride) {
        int nn = e >> 9, lane = (e >> 3) & 63, j = e & 7;
        int col = nn * 16 + (lane & 15), k = (lane >> 4) * 8 + j;
        wf16[1024 + e] = (_Float16)W2[k * 64 + col];
        wf16[3072 + e] = (_Float16)W2[(k + 32) * 64 + col];
    }
    for (int e = tid; e < 4096; e += stride) {
        int nn = e >> 9, lane = (e >> 3) & 63, j = e & 7;
        int col = nn * 16 + (lane & 15), k = (lane >> 4) * 8 + j;
        wf16[5120 + e] = (_Float16)W3[k * 128 + col];
        wf16[9216 + e] = (_Float16)W3[(k + 32) * 128 + col];
    }
    grid.sync();

    // ---- phase 2: CSR offsets, blocks 0..NC/CHUNK-1, one 250-cell chunk --
    if (blockIdx.x < NC / CHUNK) {
        int i = blockIdx.x * CHUNK + t;
        int c = (t < CHUNK) ? cellCnt[i] : 0;
        sc[t] = c;
        __syncthreads();
        for (int d = 1; d < 256; d <<= 1) {
            int o = (t >= d) ? sc[t - d] : 0;
            __syncthreads();
            sc[t] += o;
            __syncthreads();
        }
        if (t == 255) base_s = atomicAdd(cursor, sc[255]);
        __syncthreads();
        int start = base_s + sc[t] - c;
        if (t < CHUNK) {
            cellStart[i] = start;
            cellEnd[i] = start + c;
            cellCur[i] = start;
        }
    }
    grid.sync();

    // ---- phase 3: scatter (pid packed in w) + cpos4 ----
    for (int p = tid; p < N; p += stride) {
        float x = vtx[3 * p], y = vtx[3 * p + 1], z = vtx[3 * p + 2];
        int cc = (cellcoord(z) * GD + cellcoord(y)) * GD + cellcoord(x);
        int pos = atomicAdd(&cellCur[cc], 1);
        sorted4[pos] = make_float4(x, y, z, __int_as_float(p));
    }
    for (int p = tid; p < M; p += stride) {
        int i = cidx[p];
        float x = vtx[3 * i], y = vtx[3 * i + 1], z = vtx[3 * i + 2];
        float sn = fmaf(z, z, fmaf(y, y, x * x));
        cpos4[p] = make_float4(x, y, z, sn);
    }
}

// -------- K2: fused 4-wave cooperative collect + top-64 + MLP -------------
__global__ __launch_bounds__(256) void sa_fused4_kernel(
    const float4* __restrict__ cpos4, const float4* __restrict__ sorted4,
    const int* __restrict__ cellStart, const int* __restrict__ cellEnd,
    const _Float16* __restrict__ wf16,
    const float* __restrict__ b1, const float* __restrict__ b2,
    const float* __restrict__ b3, float* __restrict__ out) {

    __shared__ __align__(16) ull key[CAPK];          // 2 KB
    __shared__ __align__(16) float4 pos_s[CAPK];     // 4 KB
    __shared__ __align__(16) _Float16 featb[1024];   // 2 KB
    __shared__ __align__(16) _Float16 h1[4096];      // 8 KB
    __shared__ __align__(16) _Float16 h2[4096];      // 8 KB
    __shared__ int selb[64];
    __shared__ int chdesc[64];
    __shared__ int scnt_s;

    int t = threadIdx.x, w = t >> 6, lane = t & 63;
    int r16 = lane & 15, g = lane >> 4;
    int c = blockIdx.x;
    float4 cc = cpos4[c];

    key[t] = ~0ull;
    if (t == 0) scnt_s = 0;

    int cx = cellcoord(cc.x), cy = cellcoord(cc.y), cz = cellcoord(cc.z);
    int x0 = max(cx - 1, 0), x1 = min(cx + 1, GD - 1), lx = x1 - x0 + 1;
    int y0 = max(cy - 1, 0), y1 = min(cy + 1, GD - 1), ly = y1 - y0 + 1;
    int z0 = max(cz - 1, 0), z1 = min(cz + 1, GD - 1), lz = z1 - z0 + 1;
    int nrow = ly * lz;

    int rstart = 0, rlen = 0;
    if (lane < nrow) {
        int iy = lane % ly, iz = lane / ly;
        int gy = y0 + iy, gz = z0 + iz;
        float ylo = (gy == 0) ? -1e30f : gy * 0.2f - 5.0f;
        float yhi = (gy == GD - 1) ? 1e30f : (gy + 1) * 0.2f - 5.0f;
        float zlo = (gz == 0) ? -1e30f : gz * 0.2f - 5.0f;
        float zhi = (gz == GD - 1) ? 1e30f : (gz + 1) * 0.2f - 5.0f;
        float dy = fmaxf(0.f, fmaxf(ylo - cc.y, cc.y - yhi));
        float dz = fmaxf(0.f, fmaxf(zlo - cc.z, cc.z - zhi));
        if (fmaf(dz, dz, dy * dy) <= R2SAFE) {
            int cell0 = (gz * GD + gy) * GD + x0;
            int cellL = cell0 + (lx - 1);
            rstart = cellStart[cell0];
            rlen = cellEnd[cellL] - rstart;
        }
    }
    int nch = (rlen + 63) >> 6;
    int ip = nch;
#pragma unroll
    for (int d = 1; d < 16; d <<= 1) {
        int o = __shfl_up(ip, d);
        if (lane >= d) ip += o;
    }
    int C = __shfl(ip, nrow - 1);
    int ebase = ip - nch;
    if (w == 0 && lane < nrow) {
        for (int k = 0; k < nch; ++k) {
            int st = rstart + (k << 6);
            int ln = min(64, rlen - (k << 6));
            chdesc[ebase + k] = st | (ln << 20);
        }
    }
    __syncthreads();

    // stream chunks, 4 waves round-robin
    for (int ch = w; ch < C; ch += 4) {
        int d0 = chdesc[ch];
        int st = d0 & 0xFFFFF, ln = d0 >> 20;
        if (lane < ln) {
            int sp = st + lane;
            float4 p = sorted4[sp];
            float psn = fmaf(p.z, p.z, fmaf(p.y, p.y, p.x * p.x));
            float dot = fmaf(p.z, cc.z, fmaf(p.y, cc.y, p.x * cc.x));
            float tt = fmaf(-2.f, dot, cc.w) + psn;
            if (tt <= R2SAFE) {
                float dd = sqrtf(fabsf(tt));
                if (dd <= RADIUS_F) {
                    int pid = __float_as_int(p.w);
                    int slot = atomicAdd(&scnt_s, 1);
                    if (slot < CAPK) {
                        key[slot] = (((ull)__float_as_uint(dd)) << 32) | (unsigned)pid;
                        pos_s[slot] = p;
                    }
                }
            }
        }
    }
    __syncthreads();

    // per-wave weight slices (latency hides under rank-select)
    f16x4 F1  = ((const f16x4*)wf16)[w * 64 + lane];
    f16x8 FA2 = ((const f16x8*)(wf16 + 1024))[w * 64 + lane];
    f16x8 FB2 = ((const f16x8*)(wf16 + 3072))[w * 64 + lane];
    f16x8 FA3a = ((const f16x8*)(wf16 + 5120))[(2 * w + 0) * 64 + lane];
    f16x8 FA3b = ((const f16x8*)(wf16 + 5120))[(2 * w + 1) * 64 + lane];
    f16x8 FB3a = ((const f16x8*)(wf16 + 9216))[(2 * w + 0) * 64 + lane];
    f16x8 FB3b = ((const f16x8*)(wf16 + 9216))[(2 * w + 1) * 64 + lane];
    float B1 = b1[w * 16 + r16];
    float B2 = b2[w * 16 + r16];
    float B3a = b3[(2 * w + 0) * 16 + r16];
    float B3b = b3[(2 * w + 1) * 16 + r16];

    // top-64: 256-thread padded unroll-8 rank (selb = slot index)
    int n = min(scnt_s, CAPK);
    int nsel = min(n, 64);
    int n64 = (n + 63) & ~63;
    if (n > 64) {
        for (int i = t; i < n; i += 256) {
            ull ki = key[i];
            int r = 0;
            for (int j = 0; j < n64; j += 8) {
#pragma unroll
                for (int jj = 0; jj < 8; ++jj)
                    r += (key[j + jj] < ki) ? 1 : 0;
            }
            if (r < 64) selb[r] = i;
        }
    } else {
        for (int i = t; i < n; i += 256) selb[i] = i;
    }
    __syncthreads();

    // feature rows -> featb [64][16] f16, zero-padded
    if (t < 64) {
        _Float16 z = (_Float16)0.f;
        f16x8 lo8 = {z, z, z, z, z, z, z, z};
        if (t < nsel) {
            float4 p = pos_s[selb[t]];
            lo8[0] = (_Float16)p.x; lo8[1] = (_Float16)p.y; lo8[2] = (_Float16)p.z;
            lo8[3] = (_Float16)(p.x - cc.x);
            lo8[4] = (_Float16)(p.y - cc.y);
            lo8[5] = (_Float16)(p.z - cc.z);
        }
        f16x8 hi8 = {z, z, z, z, z, z, z, z};
        *(f16x8*)&featb[t * 16 + 0] = lo8;
        *(f16x8*)&featb[t * 16 + 8] = hi8;
    }
    __syncthreads();

    // L1: featb @ W1 -> relu -> h1
    {
        f16x4 a1[4];
#pragma unroll
        for (int m = 0; m < 4; ++m)
            a1[m] = *(const f16x4*)&featb[(m * 16 + r16) * 16 + g * 4];
        int col = w * 16 + r16;
#pragma unroll
        for (int m = 0; m < 4; ++m) {
            f32x4 acc = {B1, B1, B1, B1};
            acc = __builtin_amdgcn_mfma_f32_16x16x16f16(a1[m], F1, acc, 0, 0, 0);
#pragma unroll
            for (int reg = 0; reg < 4; ++reg) {
                int row = m * 16 + g * 4 + reg;
                h1[row * 64 + (col ^ ((row & 7) << 3))] =
                    (_Float16)fmaxf(acc[reg], 0.f);
            }
        }
    }
    __syncthreads();

    // L2: read h1, write h2
    {
        int col = w * 16 + r16;
#pragma unroll
        for (int m = 0; m < 4; ++m) {
            int row = m * 16 + r16;
            f16x8 aA = *(const f16x8*)&h1[row * 64 + ((g * 8) ^ ((row & 7) << 3))];
            f16x8 aB = *(const f16x8*)&h1[row * 64 + ((32 + g * 8) ^ ((row & 7) << 3))];
            f32x4 acc = {B2, B2, B2, B2};
            acc = __builtin_amdgcn_mfma_f32_16x16x32_f16(aA, FA2, acc, 0, 0, 0);
            acc = __builtin_amdgcn_mfma_f32_16x16x32_f16(aB, FB2, acc, 0, 0, 0);
#pragma unroll
            for (int reg = 0; reg < 4; ++reg) {
                int row2 = m * 16 + g * 4 + reg;
                h2[row2 * 64 + (col ^ ((row2 & 7) << 3))] =
                    (_Float16)fmaxf(acc[reg], 0.f);
            }
        }
    }
    __syncthreads();

    // L3: read h2; wave w -> cols (2w..2w+1)*16; masked max
    {
        f16x8 a3[4][2];
#pragma unroll
        for (int m = 0; m < 4; ++m)
#pragma unroll
            for (int kt = 0; kt < 2; ++kt) {
                int row = m * 16 + r16;
                int k0 = kt * 32 + g * 8;
                a3[m][kt] = *(const f16x8*)&h2[row * 64 + (k0 ^ ((row & 7) << 3))];
            }
        float ninf = __int_as_float(0xff800000);
#pragma unroll
        for (int q = 0; q < 2; ++q) {
            float bb = q ? B3b : B3a;
            f16x8 fa = q ? FA3b : FA3a;
            f16x8 fb = q ? FB3b : FB3a;
            float vm = ninf;
#pragma unroll
            for (int m = 0; m < 4; ++m) {
                f32x4 acc = {bb, bb, bb, bb};
                acc = __builtin_amdgcn_mfma_f32_16x16x32_f16(a3[m][0], fa, acc, 0, 0, 0);
                acc = __builtin_amdgcn_mfma_f32_16x16x32_f16(a3[m][1], fb, acc, 0, 0, 0);
#pragma unroll
                for (int reg = 0; reg < 4; ++reg) {
                    int row = m * 16 + g * 4 + reg;
                    if (row < nsel) vm = fmaxf(vm, acc[reg]);
                }
            }
            vm = fmaxf(vm, __shfl_xor(vm, 16));
            vm = fmaxf(vm, __shfl_xor(vm, 32));
            if (lane < 16)
                out[(size_t)c * 128 + (2 * w + q) * 16 + lane] = vm;
        }
    }
}

extern "C" void kernel_launch(void* const* d_in, const int* in_sizes, int n_in,
                              void* d_out, int out_size, void* d_ws, size_t ws_size,
                              hipStream_t stream) {
    const float* vtx = (const float*)d_in[0];
    const int* cidx  = (const int*)d_in[1];
    const float* W1  = (const float*)d_in[2];
    const float* b1  = (const float*)d_in[3];
    const float* W2  = (const float*)d_in[4];
    const float* b2  = (const float*)d_in[5];
    const float* W3  = (const float*)d_in[6];
    const float* b3  = (const float*)d_in[7];
    float* out = (float*)d_out;

    int N = in_sizes[0] / 3;   // 65536
    int M = in_sizes[1];       // 4096

    char* ws = (char*)d_ws;
    size_t off = 0;
    float4* sorted4 = (float4*)(ws + off); off += (size_t)N * 16;
    float4* cpos4   = (float4*)(ws + off); off += (size_t)M * 16;
    int* cellCnt    = (int*)(ws + off);    off += (size_t)NC * 4;
    int* cursor     = (int*)(ws + off);    off += 16;
    int* cellStart  = (int*)(ws + off);    off += (size_t)NC * 4;
    int* cellEnd    = (int*)(ws + off);    off += (size_t)NC * 4;
    int* cellCur    = (int*)(ws + off);    off += (size_t)NC * 4;
    _Float16* wf16  = (_Float16*)(ws + off);

    void* args[] = {
        (void*)&vtx, (void*)&cidx, (void*)&W1, (void*)&W2, (void*)&W3,
        (void*)&cellCnt, (void*)&cellStart, (void*)&cellEnd, (void*)&cellCur,
        (void*)&cursor, (void*)&sorted4, (void*)&cpos4, (void*)&wf16,
        (void*)&N, (void*)&M
    };
    hipLaunchCooperativeKernel((const void*)sa_prep_all,
                               dim3(PREPB), dim3(256), args, 0, stream);
    sa_fused4_kernel<<<M, 256, 0, stream>>>(cpos4, sorted4,
                                            cellStart, cellEnd, wf16,
                                            b1, b2, b3, out);
}

// Round 22
// 252.951 us; speedup vs baseline: 1.2622x; 1.2622x over previous
//
#include <hip/hip_runtime.h>
#include <hip/hip_bf16.h>

#define GD     50          // grid cells per dim
#define NC     (GD*GD*GD)  // 125000
#define CHUNK  250         // cells per offsets chunk; 250%50==0 keeps x-rows intact
#define NCHK   (NC/CHUNK)  // 500 chunks
#define CAPK   256         // in-radius candidate capacity per centroid
#define PREPB  1024        // prep grid; co-resident (256 CU x >=4 blocks/CU)
#define RADIUS_F 0.2f
#define R2SAFE 0.0401f
#define SCOPE_A __HIP_MEMORY_SCOPE_AGENT

typedef unsigned long long ull;
typedef __attribute__((ext_vector_type(4))) _Float16 f16x4;
typedef __attribute__((ext_vector_type(8))) _Float16 f16x8;
typedef __attribute__((ext_vector_type(4))) float    f32x4;

__device__ __forceinline__ int cellcoord(float v) {
    int c = (int)floorf((v + 5.0f) * 5.0f);
    return min(max(c, 0), GD - 1);
}

// ctrl int layout (zeroed each call by sa_zero_kernel):
//   [0,NC)        cellCnt
//   NC            cursor (unused)
//   NC+1          doneA
//   NC+2          doneB
//   NC+3          flagC
//   [NC+4,NC+504)    chunkSum (total+1; 0 = not ready)
//   [NC+504,NC+1004) chunkPre (prefix+1)
#define CTRL_INTS (NC + 1004)

// -------- K0: zero control block ------------------------------------------
__global__ void sa_zero_kernel(int4* __restrict__ dst, int n4) {
    int i = blockIdx.x * blockDim.x + threadIdx.x;
    int stride = gridDim.x * blockDim.x;
    for (; i < n4; i += stride) dst[i] = make_int4(0, 0, 0, 0);
}

// -------- K1: single-kernel prep: count+weights -> offsets -> scatter -----
// Flag-based producer-consumer sync; all PREPB blocks co-resident.
__global__ __launch_bounds__(256) void sa_prep_all(
    const float* __restrict__ vtx, const int* __restrict__ cidx,
    const float* __restrict__ W1, const float* __restrict__ W2,
    const float* __restrict__ W3,
    int* __restrict__ ctrl,
    int* __restrict__ cellStart, int* __restrict__ cellEnd,
    int* __restrict__ cellCur,
    float4* __restrict__ sorted4, float4* __restrict__ cpos4,
    _Float16* __restrict__ wf16, int N, int M) {

    __shared__ int sbuf[512];

    int t = threadIdx.x, b = blockIdx.x;
    int tid = b * 256 + t;
    int stride = PREPB * 256;

    int* cellCnt  = ctrl;
    int* doneA    = ctrl + NC + 1;
    int* doneB    = ctrl + NC + 2;
    int* flagC    = ctrl + NC + 3;
    int* chunkSum = ctrl + NC + 4;
    int* chunkPre = ctrl + NC + 504;

    // ---- phase A: count cells + pack frag-order f16 weights ----
    for (int p = tid; p < N; p += stride) {
        float x = vtx[3 * p], y = vtx[3 * p + 1], z = vtx[3 * p + 2];
        int cc = (cellcoord(z) * GD + cellcoord(y)) * GD + cellcoord(x);
        atomicAdd(&cellCnt[cc], 1);
    }
    for (int e = tid; e < 1024; e += stride) {
        int nn = e >> 8, lane = (e >> 2) & 63, j = e & 3;
        int col = nn * 16 + (lane & 15), k = (lane >> 4) * 4 + j;
        wf16[e] = (k < 6) ? (_Float16)W1[k * 64 + col] : (_Float16)0.f;
    }
    for (int e = tid; e < 2048; e += stride) {
        int nn = e >> 9, lane = (e >> 3) & 63, j = e & 7;
        int col = nn * 16 + (lane & 15), k = (lane >> 4) * 8 + j;
        wf16[1024 + e] = (_Float16)W2[k * 64 + col];
        wf16[3072 + e] = (_Float16)W2[(k + 32) * 64 + col];
    }
    for (int e = tid; e < 4096; e += stride) {
        int nn = e >> 9, lane = (e >> 3) & 63, j = e & 7;
        int col = nn * 16 + (lane & 15), k = (lane >> 4) * 8 + j;
        wf16[5120 + e] = (_Float16)W3[k * 128 + col];
        wf16[9216 + e] = (_Float16)W3[(k + 32) * 128 + col];
    }
    __syncthreads();
    if (t == 0) __hip_atomic_fetch_add(doneA, 1, __ATOMIC_RELEASE, SCOPE_A);

    // ---- phase B: chunk blocks build CSR offsets ----
    if (b < NCHK) {
        if (t == 0) {
            while (__hip_atomic_load(doneA, __ATOMIC_ACQUIRE, SCOPE_A) < PREPB)
                __builtin_amdgcn_s_sleep(8);
        }
        __syncthreads();

        int i = b * CHUNK + t;
        int cnt = (t < CHUNK)
            ? __hip_atomic_load(&cellCnt[i], __ATOMIC_RELAXED, SCOPE_A) : 0;
        sbuf[t] = cnt;
        __syncthreads();
        for (int d = 1; d < 256; d <<= 1) {
            int o = (t >= d) ? sbuf[t - d] : 0;
            __syncthreads();
            sbuf[t] += o;
            __syncthreads();
        }
        int locIncl = sbuf[t];
        int total = sbuf[255];
        if (t == 0)
            __hip_atomic_store(&chunkSum[b], total + 1, __ATOMIC_RELEASE, SCOPE_A);
        __syncthreads();

        // block 0: gather 500 chunk sums, serial prefix, publish
        if (b == 0) {
            for (int j = t; j < NCHK; j += 256) {
                int v;
                do {
                    v = __hip_atomic_load(&chunkSum[j], __ATOMIC_RELAXED, SCOPE_A);
                    if (v == 0) __builtin_amdgcn_s_sleep(2);
                } while (v == 0);
                sbuf[j < 500 ? j : 0] = v - 1;   // j<500 always
            }
            __syncthreads();
            if (t == 0) {
                int run = 0;
                for (int j = 0; j < NCHK; ++j) {
                    int v = sbuf[j];
                    sbuf[j] = run;
                    run += v;
                }
            }
            __syncthreads();
            for (int j = t; j < NCHK; j += 256)
                __hip_atomic_store(&chunkPre[j], sbuf[j] + 1, __ATOMIC_RELAXED, SCOPE_A);
            __threadfence();
            __syncthreads();
            if (t == 0)
                __hip_atomic_store(flagC, 1, __ATOMIC_RELEASE, SCOPE_A);
        }

        if (t == 0) {
            while (__hip_atomic_load(flagC, __ATOMIC_ACQUIRE, SCOPE_A) == 0)
                __builtin_amdgcn_s_sleep(8);
        }
        __syncthreads();
        int base = __hip_atomic_load(&chunkPre[b], __ATOMIC_RELAXED, SCOPE_A) - 1;
        int start = base + locIncl - cnt;
        if (t < CHUNK) {
            cellStart[i] = start;                 // consumed post-boundary
            cellEnd[i] = start + cnt;             // consumed post-boundary
            __hip_atomic_store(&cellCur[i], start, __ATOMIC_RELAXED, SCOPE_A);
        }
        __syncthreads();
        if (t == 0) __hip_atomic_fetch_add(doneB, 1, __ATOMIC_RELEASE, SCOPE_A);
    }

    // ---- phase C: wait offsets done, then scatter + cpos4 ----
    if (t == 0) {
        while (__hip_atomic_load(doneB, __ATOMIC_ACQUIRE, SCOPE_A) < NCHK)
            __builtin_amdgcn_s_sleep(8);
    }
    __syncthreads();

    for (int p = tid; p < N; p += stride) {
        float x = vtx[3 * p], y = vtx[3 * p + 1], z = vtx[3 * p + 2];
        int cc = (cellcoord(z) * GD + cellcoord(y)) * GD + cellcoord(x);
        int pos = atomicAdd(&cellCur[cc], 1);
        sorted4[pos] = make_float4(x, y, z, __int_as_float(p));
    }
    for (int p = tid; p < M; p += stride) {
        int i = cidx[p];
        float x = vtx[3 * i], y = vtx[3 * i + 1], z = vtx[3 * i + 2];
        float sn = fmaf(z, z, fmaf(y, y, x * x));
        cpos4[p] = make_float4(x, y, z, sn);
    }
}

// -------- K2: fused 4-wave cooperative collect + top-64 + MLP (r20) -------
__global__ __launch_bounds__(256) void sa_fused4_kernel(
    const float4* __restrict__ cpos4, const float4* __restrict__ sorted4,
    const int* __restrict__ cellStart, const int* __restrict__ cellEnd,
    const _Float16* __restrict__ wf16,
    const float* __restrict__ b1, const float* __restrict__ b2,
    const float* __restrict__ b3, float* __restrict__ out) {

    __shared__ __align__(16) ull key[CAPK];          // 2 KB
    __shared__ __align__(16) float4 pos_s[CAPK];     // 4 KB
    __shared__ __align__(16) _Float16 featb[1024];   // 2 KB
    __shared__ __align__(16) _Float16 h1[4096];      // 8 KB
    __shared__ __align__(16) _Float16 h2[4096];      // 8 KB
    __shared__ int selb[64];
    __shared__ int chdesc[64];
    __shared__ int scnt_s;

    int t = threadIdx.x, w = t >> 6, lane = t & 63;
    int r16 = lane & 15, g = lane >> 4;
    int c = blockIdx.x;
    float4 cc = cpos4[c];

    key[t] = ~0ull;
    if (t == 0) scnt_s = 0;

    int cx = cellcoord(cc.x), cy = cellcoord(cc.y), cz = cellcoord(cc.z);
    int x0 = max(cx - 1, 0), x1 = min(cx + 1, GD - 1), lx = x1 - x0 + 1;
    int y0 = max(cy - 1, 0), y1 = min(cy + 1, GD - 1), ly = y1 - y0 + 1;
    int z0 = max(cz - 1, 0), z1 = min(cz + 1, GD - 1), lz = z1 - z0 + 1;
    int nrow = ly * lz;

    int rstart = 0, rlen = 0;
    if (lane < nrow) {
        int iy = lane % ly, iz = lane / ly;
        int gy = y0 + iy, gz = z0 + iz;
        float ylo = (gy == 0) ? -1e30f : gy * 0.2f - 5.0f;
        float yhi = (gy == GD - 1) ? 1e30f : (gy + 1) * 0.2f - 5.0f;
        float zlo = (gz == 0) ? -1e30f : gz * 0.2f - 5.0f;
        float zhi = (gz == GD - 1) ? 1e30f : (gz + 1) * 0.2f - 5.0f;
        float dy = fmaxf(0.f, fmaxf(ylo - cc.y, cc.y - yhi));
        float dz = fmaxf(0.f, fmaxf(zlo - cc.z, cc.z - zhi));
        if (fmaf(dz, dz, dy * dy) <= R2SAFE) {
            int cell0 = (gz * GD + gy) * GD + x0;
            int cellL = cell0 + (lx - 1);
            rstart = cellStart[cell0];
            rlen = cellEnd[cellL] - rstart;
        }
    }
    int nch = (rlen + 63) >> 6;
    int ip = nch;
#pragma unroll
    for (int d = 1; d < 16; d <<= 1) {
        int o = __shfl_up(ip, d);
        if (lane >= d) ip += o;
    }
    int C = __shfl(ip, nrow - 1);
    int ebase = ip - nch;
    if (w == 0 && lane < nrow) {
        for (int k = 0; k < nch; ++k) {
            int st = rstart + (k << 6);
            int ln = min(64, rlen - (k << 6));
            chdesc[ebase + k] = st | (ln << 20);
        }
    }
    __syncthreads();

    // stream chunks, 4 waves round-robin
    for (int ch = w; ch < C; ch += 4) {
        int d0 = chdesc[ch];
        int st = d0 & 0xFFFFF, ln = d0 >> 20;
        if (lane < ln) {
            int sp = st + lane;
            float4 p = sorted4[sp];
            float psn = fmaf(p.z, p.z, fmaf(p.y, p.y, p.x * p.x));
            float dot = fmaf(p.z, cc.z, fmaf(p.y, cc.y, p.x * cc.x));
            float tt = fmaf(-2.f, dot, cc.w) + psn;
            if (tt <= R2SAFE) {
                float dd = sqrtf(fabsf(tt));
                if (dd <= RADIUS_F) {
                    int pid = __float_as_int(p.w);
                    int slot = atomicAdd(&scnt_s, 1);
                    if (slot < CAPK) {
                        key[slot] = (((ull)__float_as_uint(dd)) << 32) | (unsigned)pid;
                        pos_s[slot] = p;
                    }
                }
            }
        }
    }
    __syncthreads();

    // per-wave weight slices (latency hides under rank-select)
    f16x4 F1  = ((const f16x4*)wf16)[w * 64 + lane];
    f16x8 FA2 = ((const f16x8*)(wf16 + 1024))[w * 64 + lane];
    f16x8 FB2 = ((const f16x8*)(wf16 + 3072))[w * 64 + lane];
    f16x8 FA3a = ((const f16x8*)(wf16 + 5120))[(2 * w + 0) * 64 + lane];
    f16x8 FA3b = ((const f16x8*)(wf16 + 5120))[(2 * w + 1) * 64 + lane];
    f16x8 FB3a = ((const f16x8*)(wf16 + 9216))[(2 * w + 0) * 64 + lane];
    f16x8 FB3b = ((const f16x8*)(wf16 + 9216))[(2 * w + 1) * 64 + lane];
    float B1 = b1[w * 16 + r16];
    float B2 = b2[w * 16 + r16];
    float B3a = b3[(2 * w + 0) * 16 + r16];
    float B3b = b3[(2 * w + 1) * 16 + r16];

    // top-64: 256-thread padded unroll-8 rank (selb = slot index)
    int n = min(scnt_s, CAPK);
    int nsel = min(n, 64);
    int n64 = (n + 63) & ~63;
    if (n > 64) {
        for (int i = t; i < n; i += 256) {
            ull ki = key[i];
            int r = 0;
            for (int j = 0; j < n64; j += 8) {
#pragma unroll
                for (int jj = 0; jj < 8; ++jj)
                    r += (key[j + jj] < ki) ? 1 : 0;
            }
            if (r < 64) selb[r] = i;
        }
    } else {
        for (int i = t; i < n; i += 256) selb[i] = i;
    }
    __syncthreads();

    // feature rows -> featb [64][16] f16, zero-padded
    if (t < 64) {
        _Float16 z = (_Float16)0.f;
        f16x8 lo8 = {z, z, z, z, z, z, z, z};
        if (t < nsel) {
            float4 p = pos_s[selb[t]];
            lo8[0] = (_Float16)p.x; lo8[1] = (_Float16)p.y; lo8[2] = (_Float16)p.z;
            lo8[3] = (_Float16)(p.x - cc.x);
            lo8[4] = (_Float16)(p.y - cc.y);
            lo8[5] = (_Float16)(p.z - cc.z);
        }
        f16x8 hi8 = {z, z, z, z, z, z, z, z};
        *(f16x8*)&featb[t * 16 + 0] = lo8;
        *(f16x8*)&featb[t * 16 + 8] = hi8;
    }
    __syncthreads();

    // L1: featb @ W1 -> relu -> h1
    {
        f16x4 a1[4];
#pragma unroll
        for (int m = 0; m < 4; ++m)
            a1[m] = *(const f16x4*)&featb[(m * 16 + r16) * 16 + g * 4];
        int col = w * 16 + r16;
#pragma unroll
        for (int m = 0; m < 4; ++m) {
            f32x4 acc = {B1, B1, B1, B1};
            acc = __builtin_amdgcn_mfma_f32_16x16x16f16(a1[m], F1, acc, 0, 0, 0);
#pragma unroll
            for (int reg = 0; reg < 4; ++reg) {
                int row = m * 16 + g * 4 + reg;
                h1[row * 64 + (col ^ ((row & 7) << 3))] =
                    (_Float16)fmaxf(acc[reg], 0.f);
            }
        }
    }
    __syncthreads();

    // L2: read h1, write h2
    {
        int col = w * 16 + r16;
#pragma unroll
        for (int m = 0; m < 4; ++m) {
            int row = m * 16 + r16;
            f16x8 aA = *(const f16x8*)&h1[row * 64 + ((g * 8) ^ ((row & 7) << 3))];
            f16x8 aB = *(const f16x8*)&h1[row * 64 + ((32 + g * 8) ^ ((row & 7) << 3))];
            f32x4 acc = {B2, B2, B2, B2};
            acc = __builtin_amdgcn_mfma_f32_16x16x32_f16(aA, FA2, acc, 0, 0, 0);
            acc = __builtin_amdgcn_mfma_f32_16x16x32_f16(aB, FB2, acc, 0, 0, 0);
#pragma unroll
            for (int reg = 0; reg < 4; ++reg) {
                int row2 = m * 16 + g * 4 + reg;
                h2[row2 * 64 + (col ^ ((row2 & 7) << 3))] =
                    (_Float16)fmaxf(acc[reg], 0.f);
            }
        }
    }
    __syncthreads();

    // L3: read h2; wave w -> cols (2w..2w+1)*16; masked max
    {
        f16x8 a3[4][2];
#pragma unroll
        for (int m = 0; m < 4; ++m)
#pragma unroll
            for (int kt = 0; kt < 2; ++kt) {
                int row = m * 16 + r16;
                int k0 = kt * 32 + g * 8;
                a3[m][kt] = *(const f16x8*)&h2[row * 64 + (k0 ^ ((row & 7) << 3))];
            }
        float ninf = __int_as_float(0xff800000);
#pragma unroll
        for (int q = 0; q < 2; ++q) {
            float bb = q ? B3b : B3a;
            f16x8 fa = q ? FA3b : FA3a;
            f16x8 fb = q ? FB3b : FB3a;
            float vm = ninf;
#pragma unroll
            for (int m = 0; m < 4; ++m) {
                f32x4 acc = {bb, bb, bb, bb};
                acc = __builtin_amdgcn_mfma_f32_16x16x32_f16(a3[m][0], fa, acc, 0, 0, 0);
                acc = __builtin_amdgcn_mfma_f32_16x16x32_f16(a3[m][1], fb, acc, 0, 0, 0);
#pragma unroll
                for (int reg = 0; reg < 4; ++reg) {
                    int row = m * 16 + g * 4 + reg;
                    if (row < nsel) vm = fmaxf(vm, acc[reg]);
                }
            }
            vm = fmaxf(vm, __shfl_xor(vm, 16));
            vm = fmaxf(vm, __shfl_xor(vm, 32));
            if (lane < 16)
                out[(size_t)c * 128 + (2 * w + q) * 16 + lane] = vm;
        }
    }
}

extern "C" void kernel_launch(void* const* d_in, const int* in_sizes, int n_in,
                              void* d_out, int out_size, void* d_ws, size_t ws_size,
                              hipStream_t stream) {
    const float* vtx = (const float*)d_in[0];
    const int* cidx  = (const int*)d_in[1];
    const float* W1  = (const float*)d_in[2];
    const float* b1  = (const float*)d_in[3];
    const float* W2  = (const float*)d_in[4];
    const float* b2  = (const float*)d_in[5];
    const float* W3  = (const float*)d_in[6];
    const float* b3  = (const float*)d_in[7];
    float* out = (float*)d_out;

    int N = in_sizes[0] / 3;   // 65536
    int M = in_sizes[1];       // 4096

    char* ws = (char*)d_ws;
    size_t off = 0;
    float4* sorted4 = (float4*)(ws + off); off += (size_t)N * 16;
    float4* cpos4   = (float4*)(ws + off); off += (size_t)M * 16;
    int* ctrl       = (int*)(ws + off);    off += ((size_t)CTRL_INTS * 4 + 15) & ~15ull;
    int* cellStart  = (int*)(ws + off);    off += (size_t)NC * 4;
    int* cellEnd    = (int*)(ws + off);    off += (size_t)NC * 4;
    int* cellCur    = (int*)(ws + off);    off += (size_t)NC * 4;
    _Float16* wf16  = (_Float16*)(ws + off);

    sa_zero_kernel<<<256, 256, 0, stream>>>((int4*)ctrl, (CTRL_INTS * 4 + 15) / 16);
    sa_prep_all<<<PREPB, 256, 0, stream>>>(vtx, cidx, W1, W2, W3, ctrl,
                                           cellStart, cellEnd, cellCur,
                                           sorted4, cpos4, wf16, N, M);
    sa_fused4_kernel<<<M, 256, 0, stream>>>(cpos4, sorted4,
                                            cellStart, cellEnd, wf16,
                                            b1, b2, b3, out);
}

// Round 23
// 63.489 us; speedup vs baseline: 5.0287x; 3.9842x over previous
//
#include <hip/hip_runtime.h>
#include <hip/hip_bf16.h>

#define GD     50          // grid cells per dim
#define NC     (GD*GD*GD)  // 125000
#define CHUNK  250         // cells per offsets chunk; 250%50==0 keeps x-rows intact
#define CAPK   256         // in-radius candidate capacity per centroid
#define RADIUS_F 0.2f
#define R2SAFE 0.0401f

typedef unsigned long long ull;
typedef __attribute__((ext_vector_type(4))) _Float16 f16x4;
typedef __attribute__((ext_vector_type(8))) _Float16 f16x8;
typedef __attribute__((ext_vector_type(4))) float    f32x4;

__device__ __forceinline__ int cellcoord(float v) {
    int c = (int)floorf((v + 5.0f) * 5.0f);
    return min(max(c, 0), GD - 1);
}

// Fragment-order weight layout in wf16 (13312 f16):
//   [0,1024)      F1 [nn=4][lane=64][4]
//   [1024,3072)   FA2[nn=4][lane=64][8]
//   [3072,5120)   FB2[nn=4][lane=64][8]
//   [5120,9216)   FA3[nn=8][lane=64][8]
//   [9216,13312)  FB3[nn=8][lane=64][8]

// -------- K0: zero cellCnt+cursor AND pack frag-order f16 weights ---------
__global__ void sa_zero_kernel(int4* __restrict__ dst, int n4,
                               const float* __restrict__ W1,
                               const float* __restrict__ W2,
                               const float* __restrict__ W3,
                               _Float16* __restrict__ wf16) {
    int i = blockIdx.x * blockDim.x + threadIdx.x;
    int stride = gridDim.x * blockDim.x;
    for (int j = i; j < n4; j += stride) dst[j] = make_int4(0, 0, 0, 0);
    for (int e = i; e < 1024; e += stride) {
        int nn = e >> 8, lane = (e >> 2) & 63, j = e & 3;
        int col = nn * 16 + (lane & 15), k = (lane >> 4) * 4 + j;
        wf16[e] = (k < 6) ? (_Float16)W1[k * 64 + col] : (_Float16)0.f;
    }
    for (int e = i; e < 2048; e += stride) {
        int nn = e >> 9, lane = (e >> 3) & 63, j = e & 7;
        int col = nn * 16 + (lane & 15), k = (lane >> 4) * 8 + j;
        wf16[1024 + e] = (_Float16)W2[k * 64 + col];
        wf16[3072 + e] = (_Float16)W2[(k + 32) * 64 + col];
    }
    for (int e = i; e < 4096; e += stride) {
        int nn = e >> 9, lane = (e >> 3) & 63, j = e & 7;
        int col = nn * 16 + (lane & 15), k = (lane >> 4) * 8 + j;
        wf16[5120 + e] = (_Float16)W3[k * 128 + col];
        wf16[9216 + e] = (_Float16)W3[(k + 32) * 128 + col];
    }
}

// -------- K1: count cells (pure) ------------------------------------------
__global__ void sa_count_kernel(const float* __restrict__ vtx,
                                int* __restrict__ cellCnt, int N) {
    int i = blockIdx.x * blockDim.x + threadIdx.x;
    int stride = gridDim.x * blockDim.x;
    for (int p = i; p < N; p += stride) {
        float x = vtx[3 * p], y = vtx[3 * p + 1], z = vtx[3 * p + 2];
        int cc = (cellcoord(z) * GD + cellcoord(y)) * GD + cellcoord(x);
        atomicAdd(&cellCnt[cc], 1);
    }
}

// -------- K2: CSR offsets, 250-cell x-row-aligned chunks; also cellEnd ----
__global__ __launch_bounds__(256) void sa_offsets_kernel(
    const int* __restrict__ cellCnt, int* __restrict__ cellStart,
    int* __restrict__ cellEnd, int* __restrict__ cellCur,
    int* __restrict__ cursor) {
    __shared__ int sc[256];
    __shared__ int base_s;
    int t = threadIdx.x;
    int i = blockIdx.x * CHUNK + t;
    int c = (t < CHUNK) ? cellCnt[i] : 0;
    sc[t] = c;
    __syncthreads();
    for (int d = 1; d < 256; d <<= 1) {
        int o = (t >= d) ? sc[t - d] : 0;
        __syncthreads();
        sc[t] += o;
        __syncthreads();
    }
    if (t == 255) base_s = atomicAdd(cursor, sc[255]);
    __syncthreads();
    int start = base_s + sc[t] - c;
    if (t < CHUNK) {
        cellStart[i] = start;
        cellEnd[i] = start + c;
        cellCur[i] = start;
    }
}

// -------- K3: scatter points (pid packed in w); build cpos4 ---------------
__global__ void sa_scatter_kernel(const float* __restrict__ vtx,
                                  int* __restrict__ cellCur,
                                  float4* __restrict__ sorted4,
                                  const int* __restrict__ cidx,
                                  float4* __restrict__ cpos4,
                                  int N, int M) {
    int p = blockIdx.x * blockDim.x + threadIdx.x;
    if (p < N) {
        float x = vtx[3 * p], y = vtx[3 * p + 1], z = vtx[3 * p + 2];
        int cc = (cellcoord(z) * GD + cellcoord(y)) * GD + cellcoord(x);
        int pos = atomicAdd(&cellCur[cc], 1);
        sorted4[pos] = make_float4(x, y, z, __int_as_float(p));
    }
    if (p < M) {
        int i = cidx[p];
        float x = vtx[3 * i], y = vtx[3 * i + 1], z = vtx[3 * i + 2];
        float sn = fmaf(z, z, fmaf(y, y, x * x));
        cpos4[p] = make_float4(x, y, z, sn);
    }
}

// -------- K4: fused 4-wave cooperative collect + top-64 + MLP -------------
__global__ __launch_bounds__(256) void sa_fused4_kernel(
    const float4* __restrict__ cpos4, const float4* __restrict__ sorted4,
    const int* __restrict__ cellStart, const int* __restrict__ cellEnd,
    const _Float16* __restrict__ wf16,
    const float* __restrict__ b1, const float* __restrict__ b2,
    const float* __restrict__ b3, float* __restrict__ out) {

    __shared__ __align__(16) ull key[CAPK];          // 2 KB
    __shared__ __align__(16) float4 pos_s[CAPK];     // 4 KB
    __shared__ __align__(16) _Float16 h1[4096];      // 8 KB
    __shared__ __align__(16) _Float16 h2[4096];      // 8 KB
    __shared__ int selb[64];
    __shared__ int chdesc[64];
    __shared__ int scnt_s;

    int t = threadIdx.x, w = t >> 6, lane = t & 63;
    int r16 = lane & 15, g = lane >> 4;
    int c = blockIdx.x;
    float4 cc = cpos4[c];

    key[t] = ~0ull;
    if (t == 0) scnt_s = 0;

    int cx = cellcoord(cc.x), cy = cellcoord(cc.y), cz = cellcoord(cc.z);
    int x0 = max(cx - 1, 0), x1 = min(cx + 1, GD - 1), lx = x1 - x0 + 1;
    int y0 = max(cy - 1, 0), y1 = min(cy + 1, GD - 1), ly = y1 - y0 + 1;
    int z0 = max(cz - 1, 0), z1 = min(cz + 1, GD - 1), lz = z1 - z0 + 1;
    int nrow = ly * lz;

    int rstart = 0, rlen = 0;
    if (lane < nrow) {
        int iy = lane % ly, iz = lane / ly;
        int gy = y0 + iy, gz = z0 + iz;
        float ylo = (gy == 0) ? -1e30f : gy * 0.2f - 5.0f;
        float yhi = (gy == GD - 1) ? 1e30f : (gy + 1) * 0.2f - 5.0f;
        float zlo = (gz == 0) ? -1e30f : gz * 0.2f - 5.0f;
        float zhi = (gz == GD - 1) ? 1e30f : (gz + 1) * 0.2f - 5.0f;
        float dy = fmaxf(0.f, fmaxf(ylo - cc.y, cc.y - yhi));
        float dz = fmaxf(0.f, fmaxf(zlo - cc.z, cc.z - zhi));
        if (fmaf(dz, dz, dy * dy) <= R2SAFE) {
            int cell0 = (gz * GD + gy) * GD + x0;
            int cellL = cell0 + (lx - 1);
            rstart = cellStart[cell0];
            rlen = cellEnd[cellL] - rstart;
        }
    }
    int nch = (rlen + 63) >> 6;
    int ip = nch;
#pragma unroll
    for (int d = 1; d < 16; d <<= 1) {
        int o = __shfl_up(ip, d);
        if (lane >= d) ip += o;
    }
    int C = __shfl(ip, nrow - 1);
    int ebase = ip - nch;
    if (w == 0 && lane < nrow) {
        for (int k = 0; k < nch; ++k) {
            int st = rstart + (k << 6);
            int ln = min(64, rlen - (k << 6));
            chdesc[ebase + k] = st | (ln << 20);
        }
    }
    __syncthreads();

    // stream chunks, 4 waves round-robin
    for (int ch = w; ch < C; ch += 4) {
        int d0 = chdesc[ch];
        int st = d0 & 0xFFFFF, ln = d0 >> 20;
        if (lane < ln) {
            int sp = st + lane;
            float4 p = sorted4[sp];
            float psn = fmaf(p.z, p.z, fmaf(p.y, p.y, p.x * p.x));
            float dot = fmaf(p.z, cc.z, fmaf(p.y, cc.y, p.x * cc.x));
            float tt = fmaf(-2.f, dot, cc.w) + psn;
            if (tt <= R2SAFE) {
                float dd = sqrtf(fabsf(tt));
                if (dd <= RADIUS_F) {
                    int pid = __float_as_int(p.w);
                    int slot = atomicAdd(&scnt_s, 1);
                    if (slot < CAPK) {
                        key[slot] = (((ull)__float_as_uint(dd)) << 32) | (unsigned)pid;
                        pos_s[slot] = p;
                    }
                }
            }
        }
    }
    __syncthreads();

    // per-wave weight slices (latency hides under rank-select)
    f16x4 F1  = ((const f16x4*)wf16)[w * 64 + lane];
    f16x8 FA2 = ((const f16x8*)(wf16 + 1024))[w * 64 + lane];
    f16x8 FB2 = ((const f16x8*)(wf16 + 3072))[w * 64 + lane];
    f16x8 FA3a = ((const f16x8*)(wf16 + 5120))[(2 * w + 0) * 64 + lane];
    f16x8 FA3b = ((const f16x8*)(wf16 + 5120))[(2 * w + 1) * 64 + lane];
    f16x8 FB3a = ((const f16x8*)(wf16 + 9216))[(2 * w + 0) * 64 + lane];
    f16x8 FB3b = ((const f16x8*)(wf16 + 9216))[(2 * w + 1) * 64 + lane];
    float B1 = b1[w * 16 + r16];
    float B2 = b2[w * 16 + r16];
    float B3a = b3[(2 * w + 0) * 16 + r16];
    float B3b = b3[(2 * w + 1) * 16 + r16];

    // top-64: 256-thread padded unroll-8 rank (selb = slot index)
    int n = min(scnt_s, CAPK);
    int nsel = min(n, 64);
    int n64 = (n + 63) & ~63;
    if (n > 64) {
        for (int i = t; i < n; i += 256) {
            ull ki = key[i];
            int r = 0;
            for (int j = 0; j < n64; j += 8) {
#pragma unroll
                for (int jj = 0; jj < 8; ++jj)
                    r += (key[j + jj] < ki) ? 1 : 0;
            }
            if (r < 64) selb[r] = i;
        }
    } else {
        for (int i = t; i < n; i += 256) selb[i] = i;
    }
    __syncthreads();

    // L1: A-frags built per-lane from selb/pos_s (no featb staging) -> h1
    {
        int col = w * 16 + r16;
#pragma unroll
        for (int m = 0; m < 4; ++m) {
            int row = m * 16 + r16;
            _Float16 z = (_Float16)0.f;
            f16x4 a = {z, z, z, z};
            if (row < nsel && g < 2) {
                float4 p = pos_s[selb[row]];
                if (g == 0) {
                    a[0] = (_Float16)p.x; a[1] = (_Float16)p.y;
                    a[2] = (_Float16)p.z; a[3] = (_Float16)(p.x - cc.x);
                } else {
                    a[0] = (_Float16)(p.y - cc.y);
                    a[1] = (_Float16)(p.z - cc.z);
                }
            }
            f32x4 acc = {B1, B1, B1, B1};
            acc = __builtin_amdgcn_mfma_f32_16x16x16f16(a, F1, acc, 0, 0, 0);
#pragma unroll
            for (int reg = 0; reg < 4; ++reg) {
                int row2 = m * 16 + g * 4 + reg;
                h1[row2 * 64 + (col ^ ((row2 & 7) << 3))] =
                    (_Float16)fmaxf(acc[reg], 0.f);
            }
        }
    }
    __syncthreads();

    // L2: read h1, write h2
    {
        int col = w * 16 + r16;
#pragma unroll
        for (int m = 0; m < 4; ++m) {
            int row = m * 16 + r16;
            f16x8 aA = *(const f16x8*)&h1[row * 64 + ((g * 8) ^ ((row & 7) << 3))];
            f16x8 aB = *(const f16x8*)&h1[row * 64 + ((32 + g * 8) ^ ((row & 7) << 3))];
            f32x4 acc = {B2, B2, B2, B2};
            acc = __builtin_amdgcn_mfma_f32_16x16x32_f16(aA, FA2, acc, 0, 0, 0);
            acc = __builtin_amdgcn_mfma_f32_16x16x32_f16(aB, FB2, acc, 0, 0, 0);
#pragma unroll
            for (int reg = 0; reg < 4; ++reg) {
                int row2 = m * 16 + g * 4 + reg;
                h2[row2 * 64 + (col ^ ((row2 & 7) << 3))] =
                    (_Float16)fmaxf(acc[reg], 0.f);
            }
        }
    }
    __syncthreads();

    // L3: read h2; wave w -> cols (2w..2w+1)*16; masked max
    {
        f16x8 a3[4][2];
#pragma unroll
        for (int m = 0; m < 4; ++m)
#pragma unroll
            for (int kt = 0; kt < 2; ++kt) {
                int row = m * 16 + r16;
                int k0 = kt * 32 + g * 8;
                a3[m][kt] = *(const f16x8*)&h2[row * 64 + (k0 ^ ((row & 7) << 3))];
            }
        float ninf = __int_as_float(0xff800000);
#pragma unroll
        for (int q = 0; q < 2; ++q) {
            float bb = q ? B3b : B3a;
            f16x8 fa = q ? FA3b : FA3a;
            f16x8 fb = q ? FB3b : FB3a;
            float vm = ninf;
#pragma unroll
            for (int m = 0; m < 4; ++m) {
                f32x4 acc = {bb, bb, bb, bb};
                acc = __builtin_amdgcn_mfma_f32_16x16x32_f16(a3[m][0], fa, acc, 0, 0, 0);
                acc = __builtin_amdgcn_mfma_f32_16x16x32_f16(a3[m][1], fb, acc, 0, 0, 0);
#pragma unroll
                for (int reg = 0; reg < 4; ++reg) {
                    int row = m * 16 + g * 4 + reg;
                    if (row < nsel) vm = fmaxf(vm, acc[reg]);
                }
            }
            vm = fmaxf(vm, __shfl_xor(vm, 16));
            vm = fmaxf(vm, __shfl_xor(vm, 32));
            if (lane < 16)
                out[(size_t)c * 128 + (2 * w + q) * 16 + lane] = vm;
        }
    }
}

extern "C" void kernel_launch(void* const* d_in, const int* in_sizes, int n_in,
                              void* d_out, int out_size, void* d_ws, size_t ws_size,
                              hipStream_t stream) {
    const float* vtx = (const float*)d_in[0];
    const int* cidx  = (const int*)d_in[1];
    const float* W1  = (const float*)d_in[2];
    const float* b1  = (const float*)d_in[3];
    const float* W2  = (const float*)d_in[4];
    const float* b2  = (const float*)d_in[5];
    const float* W3  = (const float*)d_in[6];
    const float* b3  = (const float*)d_in[7];
    float* out = (float*)d_out;

    int N = in_sizes[0] / 3;   // 65536
    int M = in_sizes[1];       // 4096

    char* ws = (char*)d_ws;
    size_t off = 0;
    float4* sorted4 = (float4*)(ws + off); off += (size_t)N * 16;
    float4* cpos4   = (float4*)(ws + off); off += (size_t)M * 16;
    int* cellCnt    = (int*)(ws + off);    off += (size_t)NC * 4;
    int* cursor     = (int*)(ws + off);    off += 16;
    int* cellStart  = (int*)(ws + off);    off += (size_t)NC * 4;
    int* cellEnd    = (int*)(ws + off);    off += (size_t)NC * 4;
    int* cellCur    = (int*)(ws + off);    off += (size_t)NC * 4;
    _Float16* wf16  = (_Float16*)(ws + off);

    sa_zero_kernel<<<256, 256, 0, stream>>>((int4*)cellCnt, (NC * 4 + 16) / 16,
                                            W1, W2, W3, wf16);
    sa_count_kernel<<<512, 256, 0, stream>>>(vtx, cellCnt, N);
    sa_offsets_kernel<<<NC / CHUNK, 256, 0, stream>>>(cellCnt, cellStart,
                                                      cellEnd, cellCur, cursor);
    sa_scatter_kernel<<<(N + 255) / 256, 256, 0, stream>>>(vtx, cellCur,
                                                           sorted4, cidx,
                                                           cpos4, N, M);
    sa_fused4_kernel<<<M, 256, 0, stream>>>(cpos4, sorted4,
                                            cellStart, cellEnd, wf16,
                                            b1, b2, b3, out);
}

// Round 24
// 60.795 us; speedup vs baseline: 5.2516x; 1.0443x over previous
//
#include <hip/hip_runtime.h>
#include <hip/hip_bf16.h>

#define GD     50          // grid cells per dim
#define NC     (GD*GD*GD)  // 125000
#define CHUNK  250         // cells per offsets chunk; 250%50==0 keeps x-rows intact
#define CAPK   256         // in-radius candidate capacity per centroid
#define RADIUS_F 0.2f
#define R2SAFE 0.0401f

typedef unsigned long long ull;
typedef __attribute__((ext_vector_type(4))) _Float16 f16x4;
typedef __attribute__((ext_vector_type(8))) _Float16 f16x8;
typedef __attribute__((ext_vector_type(4))) float    f32x4;

__device__ __forceinline__ int cellcoord(float v) {
    int c = (int)floorf((v + 5.0f) * 5.0f);
    return min(max(c, 0), GD - 1);
}

// Fragment-order weight layout in wf16 (13312 f16):
//   [0,1024)      F1 [nn=4][lane=64][4]
//   [1024,3072)   FA2[nn=4][lane=64][8]
//   [3072,5120)   FB2[nn=4][lane=64][8]
//   [5120,9216)   FA3[nn=8][lane=64][8]
//   [9216,13312)  FB3[nn=8][lane=64][8]

// -------- K0: zero cellCnt+cursor AND pack frag-order f16 weights ---------
__global__ void sa_zero_kernel(int4* __restrict__ dst, int n4,
                               const float* __restrict__ W1,
                               const float* __restrict__ W2,
                               const float* __restrict__ W3,
                               _Float16* __restrict__ wf16) {
    int i = blockIdx.x * blockDim.x + threadIdx.x;
    int stride = gridDim.x * blockDim.x;
    for (int j = i; j < n4; j += stride) dst[j] = make_int4(0, 0, 0, 0);
    for (int e = i; e < 1024; e += stride) {
        int nn = e >> 8, lane = (e >> 2) & 63, j = e & 3;
        int col = nn * 16 + (lane & 15), k = (lane >> 4) * 4 + j;
        wf16[e] = (k < 6) ? (_Float16)W1[k * 64 + col] : (_Float16)0.f;
    }
    for (int e = i; e < 2048; e += stride) {
        int nn = e >> 9, lane = (e >> 3) & 63, j = e & 7;
        int col = nn * 16 + (lane & 15), k = (lane >> 4) * 8 + j;
        wf16[1024 + e] = (_Float16)W2[k * 64 + col];
        wf16[3072 + e] = (_Float16)W2[(k + 32) * 64 + col];
    }
    for (int e = i; e < 4096; e += stride) {
        int nn = e >> 9, lane = (e >> 3) & 63, j = e & 7;
        int col = nn * 16 + (lane & 15), k = (lane >> 4) * 8 + j;
        wf16[5120 + e] = (_Float16)W3[k * 128 + col];
        wf16[9216 + e] = (_Float16)W3[(k + 32) * 128 + col];
    }
}

// -------- K1: count cells (pure) ------------------------------------------
__global__ void sa_count_kernel(const float* __restrict__ vtx,
                                int* __restrict__ cellCnt, int N) {
    int i = blockIdx.x * blockDim.x + threadIdx.x;
    int stride = gridDim.x * blockDim.x;
    for (int p = i; p < N; p += stride) {
        float x = vtx[3 * p], y = vtx[3 * p + 1], z = vtx[3 * p + 2];
        int cc = (cellcoord(z) * GD + cellcoord(y)) * GD + cellcoord(x);
        atomicAdd(&cellCnt[cc], 1);
    }
}

// -------- K2: CSR offsets, 250-cell x-row-aligned chunks; also cellEnd ----
__global__ __launch_bounds__(256) void sa_offsets_kernel(
    const int* __restrict__ cellCnt, int* __restrict__ cellStart,
    int* __restrict__ cellEnd, int* __restrict__ cellCur,
    int* __restrict__ cursor) {
    __shared__ int sc[256];
    __shared__ int base_s;
    int t = threadIdx.x;
    int i = blockIdx.x * CHUNK + t;
    int c = (t < CHUNK) ? cellCnt[i] : 0;
    sc[t] = c;
    __syncthreads();
    for (int d = 1; d < 256; d <<= 1) {
        int o = (t >= d) ? sc[t - d] : 0;
        __syncthreads();
        sc[t] += o;
        __syncthreads();
    }
    if (t == 255) base_s = atomicAdd(cursor, sc[255]);
    __syncthreads();
    int start = base_s + sc[t] - c;
    if (t < CHUNK) {
        cellStart[i] = start;
        cellEnd[i] = start + c;
        cellCur[i] = start;
    }
}

// -------- K3: scatter points (pid packed in w); build cpos4 ---------------
__global__ void sa_scatter_kernel(const float* __restrict__ vtx,
                                  int* __restrict__ cellCur,
                                  float4* __restrict__ sorted4,
                                  const int* __restrict__ cidx,
                                  float4* __restrict__ cpos4,
                                  int N, int M) {
    int p = blockIdx.x * blockDim.x + threadIdx.x;
    if (p < N) {
        float x = vtx[3 * p], y = vtx[3 * p + 1], z = vtx[3 * p + 2];
        int cc = (cellcoord(z) * GD + cellcoord(y)) * GD + cellcoord(x);
        int pos = atomicAdd(&cellCur[cc], 1);
        sorted4[pos] = make_float4(x, y, z, __int_as_float(p));
    }
    if (p < M) {
        int i = cidx[p];
        float x = vtx[3 * i], y = vtx[3 * i + 1], z = vtx[3 * i + 2];
        float sn = fmaf(z, z, fmaf(y, y, x * x));
        cpos4[p] = make_float4(x, y, z, sn);
    }
}

// -------- K4: fused 4-wave cooperative collect + top-64 + MLP (r20) -------
__global__ __launch_bounds__(256) void sa_fused4_kernel(
    const float4* __restrict__ cpos4, const float4* __restrict__ sorted4,
    const int* __restrict__ cellStart, const int* __restrict__ cellEnd,
    const _Float16* __restrict__ wf16,
    const float* __restrict__ b1, const float* __restrict__ b2,
    const float* __restrict__ b3, float* __restrict__ out) {

    __shared__ __align__(16) ull key[CAPK];          // 2 KB
    __shared__ __align__(16) float4 pos_s[CAPK];     // 4 KB
    __shared__ __align__(16) _Float16 featb[1024];   // 2 KB
    __shared__ __align__(16) _Float16 h1[4096];      // 8 KB
    __shared__ __align__(16) _Float16 h2[4096];      // 8 KB
    __shared__ int selb[64];
    __shared__ int chdesc[64];
    __shared__ int scnt_s;

    int t = threadIdx.x, w = t >> 6, lane = t & 63;
    int r16 = lane & 15, g = lane >> 4;
    int c = blockIdx.x;
    float4 cc = cpos4[c];

    key[t] = ~0ull;
    if (t == 0) scnt_s = 0;

    int cx = cellcoord(cc.x), cy = cellcoord(cc.y), cz = cellcoord(cc.z);
    int x0 = max(cx - 1, 0), x1 = min(cx + 1, GD - 1), lx = x1 - x0 + 1;
    int y0 = max(cy - 1, 0), y1 = min(cy + 1, GD - 1), ly = y1 - y0 + 1;
    int z0 = max(cz - 1, 0), z1 = min(cz + 1, GD - 1), lz = z1 - z0 + 1;
    int nrow = ly * lz;

    int rstart = 0, rlen = 0;
    if (lane < nrow) {
        int iy = lane % ly, iz = lane / ly;
        int gy = y0 + iy, gz = z0 + iz;
        float ylo = (gy == 0) ? -1e30f : gy * 0.2f - 5.0f;
        float yhi = (gy == GD - 1) ? 1e30f : (gy + 1) * 0.2f - 5.0f;
        float zlo = (gz == 0) ? -1e30f : gz * 0.2f - 5.0f;
        float zhi = (gz == GD - 1) ? 1e30f : (gz + 1) * 0.2f - 5.0f;
        float dy = fmaxf(0.f, fmaxf(ylo - cc.y, cc.y - yhi));
        float dz = fmaxf(0.f, fmaxf(zlo - cc.z, cc.z - zhi));
        if (fmaf(dz, dz, dy * dy) <= R2SAFE) {
            int cell0 = (gz * GD + gy) * GD + x0;
            int cellL = cell0 + (lx - 1);
            rstart = cellStart[cell0];
            rlen = cellEnd[cellL] - rstart;
        }
    }
    int nch = (rlen + 63) >> 6;
    int ip = nch;
#pragma unroll
    for (int d = 1; d < 16; d <<= 1) {
        int o = __shfl_up(ip, d);
        if (lane >= d) ip += o;
    }
    int C = __shfl(ip, nrow - 1);
    int ebase = ip - nch;
    if (w == 0 && lane < nrow) {
        for (int k = 0; k < nch; ++k) {
            int st = rstart + (k << 6);
            int ln = min(64, rlen - (k << 6));
            chdesc[ebase + k] = st | (ln << 20);
        }
    }
    __syncthreads();

    // stream chunks, 4 waves round-robin
    for (int ch = w; ch < C; ch += 4) {
        int d0 = chdesc[ch];
        int st = d0 & 0xFFFFF, ln = d0 >> 20;
        if (lane < ln) {
            int sp = st + lane;
            float4 p = sorted4[sp];
            float psn = fmaf(p.z, p.z, fmaf(p.y, p.y, p.x * p.x));
            float dot = fmaf(p.z, cc.z, fmaf(p.y, cc.y, p.x * cc.x));
            float tt = fmaf(-2.f, dot, cc.w) + psn;
            if (tt <= R2SAFE) {
                float dd = sqrtf(fabsf(tt));
                if (dd <= RADIUS_F) {
                    int pid = __float_as_int(p.w);
                    int slot = atomicAdd(&scnt_s, 1);
                    if (slot < CAPK) {
                        key[slot] = (((ull)__float_as_uint(dd)) << 32) | (unsigned)pid;
                        pos_s[slot] = p;
                    }
                }
            }
        }
    }
    __syncthreads();

    // per-wave weight slices (latency hides under rank-select)
    f16x4 F1  = ((const f16x4*)wf16)[w * 64 + lane];
    f16x8 FA2 = ((const f16x8*)(wf16 + 1024))[w * 64 + lane];
    f16x8 FB2 = ((const f16x8*)(wf16 + 3072))[w * 64 + lane];
    f16x8 FA3a = ((const f16x8*)(wf16 + 5120))[(2 * w + 0) * 64 + lane];
    f16x8 FA3b = ((const f16x8*)(wf16 + 5120))[(2 * w + 1) * 64 + lane];
    f16x8 FB3a = ((const f16x8*)(wf16 + 9216))[(2 * w + 0) * 64 + lane];
    f16x8 FB3b = ((const f16x8*)(wf16 + 9216))[(2 * w + 1) * 64 + lane];
    float B1 = b1[w * 16 + r16];
    float B2 = b2[w * 16 + r16];
    float B3a = b3[(2 * w + 0) * 16 + r16];
    float B3b = b3[(2 * w + 1) * 16 + r16];

    // top-64: 256-thread padded unroll-8 rank (selb = slot index)
    int n = min(scnt_s, CAPK);
    int nsel = min(n, 64);
    int n64 = (n + 63) & ~63;
    if (n > 64) {
        for (int i = t; i < n; i += 256) {
            ull ki = key[i];
            int r = 0;
            for (int j = 0; j < n64; j += 8) {
#pragma unroll
                for (int jj = 0; jj < 8; ++jj)
                    r += (key[j + jj] < ki) ? 1 : 0;
            }
            if (r < 64) selb[r] = i;
        }
    } else {
        for (int i = t; i < n; i += 256) selb[i] = i;
    }
    __syncthreads();

    // feature rows -> featb [64][16] f16, zero-padded
    if (t < 64) {
        _Float16 z = (_Float16)0.f;
        f16x8 lo8 = {z, z, z, z, z, z, z, z};
        if (t < nsel) {
            float4 p = pos_s[selb[t]];
            lo8[0] = (_Float16)p.x; lo8[1] = (_Float16)p.y; lo8[2] = (_Float16)p.z;
            lo8[3] = (_Float16)(p.x - cc.x);
            lo8[4] = (_Float16)(p.y - cc.y);
            lo8[5] = (_Float16)(p.z - cc.z);
        }
        f16x8 hi8 = {z, z, z, z, z, z, z, z};
        *(f16x8*)&featb[t * 16 + 0] = lo8;
        *(f16x8*)&featb[t * 16 + 8] = hi8;
    }
    __syncthreads();

    // L1: featb @ W1 -> relu -> h1
    {
        f16x4 a1[4];
#pragma unroll
        for (int m = 0; m < 4; ++m)
            a1[m] = *(const f16x4*)&featb[(m * 16 + r16) * 16 + g * 4];
        int col = w * 16 + r16;
#pragma unroll
        for (int m = 0; m < 4; ++m) {
            f32x4 acc = {B1, B1, B1, B1};
            acc = __builtin_amdgcn_mfma_f32_16x16x16f16(a1[m], F1, acc, 0, 0, 0);
#pragma unroll
            for (int reg = 0; reg < 4; ++reg) {
                int row = m * 16 + g * 4 + reg;
                h1[row * 64 + (col ^ ((row & 7) << 3))] =
                    (_Float16)fmaxf(acc[reg], 0.f);
            }
        }
    }
    __syncthreads();

    // L2: read h1, write h2
    {
        int col = w * 16 + r16;
#pragma unroll
        for (int m = 0; m < 4; ++m) {
            int row = m * 16 + r16;
            f16x8 aA = *(const f16x8*)&h1[row * 64 + ((g * 8) ^ ((row & 7) << 3))];
            f16x8 aB = *(const f16x8*)&h1[row * 64 + ((32 + g * 8) ^ ((row & 7) << 3))];
            f32x4 acc = {B2, B2, B2, B2};
            acc = __builtin_amdgcn_mfma_f32_16x16x32_f16(aA, FA2, acc, 0, 0, 0);
            acc = __builtin_amdgcn_mfma_f32_16x16x32_f16(aB, FB2, acc, 0, 0, 0);
#pragma unroll
            for (int reg = 0; reg < 4; ++reg) {
                int row2 = m * 16 + g * 4 + reg;
                h2[row2 * 64 + (col ^ ((row2 & 7) << 3))] =
                    (_Float16)fmaxf(acc[reg], 0.f);
            }
        }
    }
    __syncthreads();

    // L3: read h2; wave w -> cols (2w..2w+1)*16; masked max
    {
        f16x8 a3[4][2];
#pragma unroll
        for (int m = 0; m < 4; ++m)
#pragma unroll
            for (int kt = 0; kt < 2; ++kt) {
                int row = m * 16 + r16;
                int k0 = kt * 32 + g * 8;
                a3[m][kt] = *(const f16x8*)&h2[row * 64 + (k0 ^ ((row & 7) << 3))];
            }
        float ninf = __int_as_float(0xff800000);
#pragma unroll
        for (int q = 0; q < 2; ++q) {
            float bb = q ? B3b : B3a;
            f16x8 fa = q ? FA3b : FA3a;
            f16x8 fb = q ? FB3b : FB3a;
            float vm = ninf;
#pragma unroll
            for (int m = 0; m < 4; ++m) {
                f32x4 acc = {bb, bb, bb, bb};
                acc = __builtin_amdgcn_mfma_f32_16x16x32_f16(a3[m][0], fa, acc, 0, 0, 0);
                acc = __builtin_amdgcn_mfma_f32_16x16x32_f16(a3[m][1], fb, acc, 0, 0, 0);
#pragma unroll
                for (int reg = 0; reg < 4; ++reg) {
                    int row = m * 16 + g * 4 + reg;
                    if (row < nsel) vm = fmaxf(vm, acc[reg]);
                }
            }
            vm = fmaxf(vm, __shfl_xor(vm, 16));
            vm = fmaxf(vm, __shfl_xor(vm, 32));
            if (lane < 16)
                out[(size_t)c * 128 + (2 * w + q) * 16 + lane] = vm;
        }
    }
}

extern "C" void kernel_launch(void* const* d_in, const int* in_sizes, int n_in,
                              void* d_out, int out_size, void* d_ws, size_t ws_size,
                              hipStream_t stream) {
    const float* vtx = (const float*)d_in[0];
    const int* cidx  = (const int*)d_in[1];
    const float* W1  = (const float*)d_in[2];
    const float* b1  = (const float*)d_in[3];
    const float* W2  = (const float*)d_in[4];
    const float* b2  = (const float*)d_in[5];
    const float* W3  = (const float*)d_in[6];
    const float* b3  = (const float*)d_in[7];
    float* out = (float*)d_out;

    int N = in_sizes[0] / 3;   // 65536
    int M = in_sizes[1];       // 4096

    char* ws = (char*)d_ws;
    size_t off = 0;
    float4* sorted4 = (float4*)(ws + off); off += (size_t)N * 16;
    float4* cpos4   = (float4*)(ws + off); off += (size_t)M * 16;
    int* cellCnt    = (int*)(ws + off);    off += (size_t)NC * 4;
    int* cursor     = (int*)(ws + off);    off += 16;
    int* cellStart  = (int*)(ws + off);    off += (size_t)NC * 4;
    int* cellEnd    = (int*)(ws + off);    off += (size_t)NC * 4;
    int* cellCur    = (int*)(ws + off);    off += (size_t)NC * 4;
    _Float16* wf16  = (_Float16*)(ws + off);

    sa_zero_kernel<<<256, 256, 0, stream>>>((int4*)cellCnt, (NC * 4 + 16) / 16,
                                            W1, W2, W3, wf16);
    sa_count_kernel<<<512, 256, 0, stream>>>(vtx, cellCnt, N);
    sa_offsets_kernel<<<NC / CHUNK, 256, 0, stream>>>(cellCnt, cellStart,
                                                      cellEnd, cellCur, cursor);
    sa_scatter_kernel<<<(N + 255) / 256, 256, 0, stream>>>(vtx, cellCur,
                                                           sorted4, cidx,
                                                           cpos4, N, M);
    sa_fused4_kernel<<<M, 256, 0, stream>>>(cpos4, sorted4,
                                            cellStart, cellEnd, wf16,
                                            b1, b2, b3, out);
}